// Round 6
// baseline (669.308 us; speedup 1.0000x reference)
//
#include <hip/hip_runtime.h>

#define N_NODES_C 100000
#define N_EDGES_C 1600000
#define IN_F 128
#define OUT_F 64
#define NPB 64                                    // nodes per bucket (power of 2)
#define NBUK ((N_NODES_C + NPB - 1) / NPB)        // 1563 buckets

// ---------------- GEMM: h[n][64] = x[n][128] @ W[64][128]^T + b ----------------
// 64 nodes/block, 256 threads, 4x4 register tile (4 nodes x 4 outs).
__global__ __launch_bounds__(256) void gemm_kernel(
    const float* __restrict__ x, const float* __restrict__ W,
    const float* __restrict__ bias, float* __restrict__ h, int n) {
  __shared__ float Wt[IN_F * OUT_F];   // [k][o], stride 64, 32 KB

  const int t = threadIdx.x;
  {
    const int o = t & 63;
    const int k4base = t >> 6;                       // 0..3
    const float4* Wrow = (const float4*)(W + o * IN_F);
#pragma unroll
    for (int i = 0; i < 8; ++i) {
      int k4 = k4base + i * 4;                       // 0..31
      float4 v = Wrow[k4];
      int k = k4 * 4;
      Wt[(k + 0) * OUT_F + o] = v.x;
      Wt[(k + 1) * OUT_F + o] = v.y;
      Wt[(k + 2) * OUT_F + o] = v.z;
      Wt[(k + 3) * OUT_F + o] = v.w;
    }
  }
  __syncthreads();

  const int tx = t & 15;               // output quad
  const int ty = t >> 4;               // node group
  const int node0 = blockIdx.x * 64 + ty * 4;

  bool v0 = node0 + 0 < n, v1 = node0 + 1 < n, v2 = node0 + 2 < n, v3 = node0 + 3 < n;
  const float4* xr0 = (const float4*)(x + (size_t)(v0 ? node0 + 0 : 0) * IN_F);
  const float4* xr1 = (const float4*)(x + (size_t)(v1 ? node0 + 1 : 0) * IN_F);
  const float4* xr2 = (const float4*)(x + (size_t)(v2 ? node0 + 2 : 0) * IN_F);
  const float4* xr3 = (const float4*)(x + (size_t)(v3 ? node0 + 3 : 0) * IN_F);

  float4 acc0 = make_float4(0.f, 0.f, 0.f, 0.f);
  float4 acc1 = acc0, acc2 = acc0, acc3 = acc0;
  const float4* Wt4 = (const float4*)Wt;   // Wt4[k*16 + tx]

#pragma unroll 2
  for (int kc = 0; kc < 32; ++kc) {
    float4 xv0 = xr0[kc];
    float4 xv1 = xr1[kc];
    float4 xv2 = xr2[kc];
    float4 xv3 = xr3[kc];
    float4 w0 = Wt4[(kc * 4 + 0) * 16 + tx];
    float4 w1 = Wt4[(kc * 4 + 1) * 16 + tx];
    float4 w2 = Wt4[(kc * 4 + 2) * 16 + tx];
    float4 w3 = Wt4[(kc * 4 + 3) * 16 + tx];
#define FMA4(A, XV)                                            \
    A.x += XV.x * w0.x + XV.y * w1.x + XV.z * w2.x + XV.w * w3.x; \
    A.y += XV.x * w0.y + XV.y * w1.y + XV.z * w2.y + XV.w * w3.y; \
    A.z += XV.x * w0.z + XV.y * w1.z + XV.z * w2.z + XV.w * w3.z; \
    A.w += XV.x * w0.w + XV.y * w1.w + XV.z * w2.w + XV.w * w3.w;
    FMA4(acc0, xv0)
    FMA4(acc1, xv1)
    FMA4(acc2, xv2)
    FMA4(acc3, xv3)
#undef FMA4
  }

  const float4 bv = ((const float4*)bias)[tx];
  acc0.x += bv.x; acc0.y += bv.y; acc0.z += bv.z; acc0.w += bv.w;
  acc1.x += bv.x; acc1.y += bv.y; acc1.z += bv.z; acc1.w += bv.w;
  acc2.x += bv.x; acc2.y += bv.y; acc2.z += bv.z; acc2.w += bv.w;
  acc3.x += bv.x; acc3.y += bv.y; acc3.z += bv.z; acc3.w += bv.w;

  if (v0) ((float4*)(h + (size_t)(node0 + 0) * OUT_F))[tx] = acc0;
  if (v1) ((float4*)(h + (size_t)(node0 + 1) * OUT_F))[tx] = acc1;
  if (v2) ((float4*)(h + (size_t)(node0 + 2) * OUT_F))[tx] = acc2;
  if (v3) ((float4*)(h + (size_t)(node0 + 3) * OUT_F))[tx] = acc3;
}

// ---------------- CSR build ----------------
__global__ __launch_bounds__(256) void count_kernel(
    const int* __restrict__ dst, int* __restrict__ counts, int E) {
  int e = blockIdx.x * blockDim.x + threadIdx.x;
  if (e < E) atomicAdd(&counts[dst[e]], 1);
}

#define RB 256
__global__ __launch_bounds__(RB) void reduce_kernel(
    const int* __restrict__ counts, int* __restrict__ blockSums, int n) {
  __shared__ int s[RB];
  int i = blockIdx.x * RB + threadIdx.x;
  s[threadIdx.x] = (i < n) ? counts[i] : 0;
  __syncthreads();
  for (int off = RB / 2; off > 0; off >>= 1) {
    if (threadIdx.x < off) s[threadIdx.x] += s[threadIdx.x + off];
    __syncthreads();
  }
  if (threadIdx.x == 0) blockSums[blockIdx.x] = s[0];
}

__global__ __launch_bounds__(512) void scan_partials_kernel(
    const int* __restrict__ blockSums, int* __restrict__ blockOffs, int nb,
    int* __restrict__ total_out) {
  __shared__ int s[512];
  int t = threadIdx.x;
  int v = (t < nb) ? blockSums[t] : 0;
  s[t] = v;
  __syncthreads();
  for (int off = 1; off < 512; off <<= 1) {
    int u = (t >= off) ? s[t - off] : 0;
    __syncthreads();
    s[t] += u;
    __syncthreads();
  }
  if (t < nb) blockOffs[t] = s[t] - v;      // exclusive
  if (t == 511) *total_out = s[511];        // == E -> row_ptr[N]
}

// also seeds per-bucket cursors: bcur[b] = row_ptr[b*NPB]
__global__ __launch_bounds__(RB) void scan_final_kernel(
    const int* __restrict__ counts, const int* __restrict__ blockOffs,
    int* __restrict__ row_ptr, int* __restrict__ cursor,
    int* __restrict__ bcur, int n) {
  __shared__ int s[RB];
  int i = blockIdx.x * RB + threadIdx.x;
  int v = (i < n) ? counts[i] : 0;
  s[threadIdx.x] = v;
  __syncthreads();
  for (int off = 1; off < RB; off <<= 1) {
    int u = (threadIdx.x >= off) ? s[threadIdx.x - off] : 0;
    __syncthreads();
    s[threadIdx.x] += u;
    __syncthreads();
  }
  if (i < n) {
    int ex = blockOffs[blockIdx.x] + s[threadIdx.x] - v;  // exclusive prefix
    row_ptr[i] = ex;
    cursor[i]  = ex;
    if ((i & (NPB - 1)) == 0) bcur[i / NPB] = ex;
  }
}

// Phase 1: append edges into their bucket's staging span (temporally clustered
// appends -> L2 absorbs the line fills -> dense writebacks).
__global__ __launch_bounds__(256) void bucket_scatter_kernel(
    const int* __restrict__ src, const int* __restrict__ dst,
    const float* __restrict__ w, int* __restrict__ bcur,
    int* __restrict__ stage_d, int2* __restrict__ stage_sw, int E) {
  int e = blockIdx.x * blockDim.x + threadIdx.x;
  if (e < E) {
    int d = dst[e];
    int p = atomicAdd(&bcur[d / NPB], 1);
    stage_d[p]  = d;
    stage_sw[p] = make_int2(src[e] * OUT_F, __float_as_int(w[e]));
  }
}

// Phase 2: one block per bucket; read staged records (contiguous span), place
// at exact CSR position. Read+write spans are the same ~12KB -> L2-local.
__global__ __launch_bounds__(256) void csr_place_kernel(
    const int* __restrict__ row_ptr, const int* __restrict__ stage_d,
    const int2* __restrict__ stage_sw, int* __restrict__ cursor,
    int2* __restrict__ edges, int n) {
  const int b = blockIdx.x;
  const int lo = row_ptr[b * NPB];
  const int hiNode = min((b + 1) * NPB, n);
  const int hi = row_ptr[hiNode];
  for (int i = lo + threadIdx.x; i < hi; i += blockDim.x) {
    int  d  = stage_d[i];
    int2 sw = stage_sw[i];
    int  p  = atomicAdd(&cursor[d], 1);
    edges[p] = sw;
  }
}

// ---------------- SpMM hop ----------------
__global__ __launch_bounds__(256) void spmm_kernel(
    const int* __restrict__ row_ptr, const int2* __restrict__ edges,
    const float* __restrict__ hin, float* __restrict__ hout, int n) {
  const int node = blockIdx.x * 4 + (threadIdx.x >> 6);
  const int lane = threadIdx.x & 63;
  const int grp  = lane >> 4;        // 0..3 edge group
  const int fl   = lane & 15;        // feature quad
  if (node >= n) return;
  const int beg = row_ptr[node];
  const int end = row_ptr[node + 1];

  float4 acc = make_float4(0.f, 0.f, 0.f, 0.f);
  int j = beg + grp;
  for (; j + 4 < end; j += 8) {
    int2 e0 = edges[j];
    int2 e1 = edges[j + 4];
    float4 h0 = ((const float4*)(hin + e0.x))[fl];
    float4 h1 = ((const float4*)(hin + e1.x))[fl];
    float w0 = __int_as_float(e0.y);
    float w1 = __int_as_float(e1.y);
    acc.x += w0 * h0.x + w1 * h1.x;
    acc.y += w0 * h0.y + w1 * h1.y;
    acc.z += w0 * h0.z + w1 * h1.z;
    acc.w += w0 * h0.w + w1 * h1.w;
  }
  if (j < end) {
    int2 e0 = edges[j];
    float4 h0 = ((const float4*)(hin + e0.x))[fl];
    float w0 = __int_as_float(e0.y);
    acc.x += w0 * h0.x;
    acc.y += w0 * h0.y;
    acc.z += w0 * h0.z;
    acc.w += w0 * h0.w;
  }

  acc.x += __shfl_down(acc.x, 32);
  acc.y += __shfl_down(acc.y, 32);
  acc.z += __shfl_down(acc.z, 32);
  acc.w += __shfl_down(acc.w, 32);
  acc.x += __shfl_down(acc.x, 16);
  acc.y += __shfl_down(acc.y, 16);
  acc.z += __shfl_down(acc.z, 16);
  acc.w += __shfl_down(acc.w, 16);

  if (grp == 0) {
    ((float4*)(hout + (size_t)node * OUT_F))[fl] = acc;
  }
}

extern "C" void kernel_launch(void* const* d_in, const int* in_sizes, int n_in,
                              void* d_out, int out_size, void* d_ws, size_t ws_size,
                              hipStream_t stream) {
  const float* x    = (const float*)d_in[0];
  const int*   ei   = (const int*)d_in[1];   // int32 (harness materializes ints as int32)
  const float* ew   = (const float*)d_in[2];
  const float* W    = (const float*)d_in[3];
  const float* bias = (const float*)d_in[4];
  float* out = (float*)d_out;

  const int N = N_NODES_C;
  const int E = N_EDGES_C;
  const int* src = ei;        // edge_index row 0
  const int* dst = ei + E;    // edge_index row 1
  const int NB = (N + RB - 1) / RB;   // 391 scan blocks

  char* p = (char*)d_ws;
  auto carve = [&](size_t bytes) {
    void* r = (void*)p;
    p += (bytes + 255) & ~(size_t)255;
    return r;
  };
  float* hA        = (float*)carve((size_t)N * OUT_F * 4);
  int*   counts    = (int*)  carve((size_t)N * 4);
  int*   row_ptr   = (int*)  carve((size_t)(N + 1) * 4);
  int*   cursor    = (int*)  carve((size_t)N * 4);
  int2*  edges     = (int2*) carve((size_t)E * 8);
  int*   blockSums = (int*)  carve((size_t)NB * 4);
  int*   blockOffs = (int*)  carve((size_t)NB * 4);
  int*   bcur      = (int*)  carve((size_t)NBUK * 4);

  // staging lives in d_out (free scratch until spmm hop 1 overwrites it):
  // stage_sw: E*8 = 12.8MB, stage_d: E*4 = 6.4MB  (out is 25.6MB)
  int2* stage_sw = (int2*)d_out;
  int*  stage_d  = (int*)((char*)d_out + (size_t)E * 8);

  // CSR build
  hipMemsetAsync(counts, 0, (size_t)N * 4, stream);
  count_kernel         <<<E / 256, 256, 0, stream>>>(dst, counts, E);
  reduce_kernel        <<<NB, RB, 0, stream>>>(counts, blockSums, N);
  scan_partials_kernel <<<1, 512, 0, stream>>>(blockSums, blockOffs, NB, &row_ptr[N]);
  scan_final_kernel    <<<NB, RB, 0, stream>>>(counts, blockOffs, row_ptr, cursor, bcur, N);
  bucket_scatter_kernel<<<E / 256, 256, 0, stream>>>(src, dst, ew, bcur, stage_d, stage_sw, E);
  csr_place_kernel     <<<NBUK, 256, 0, stream>>>(row_ptr, stage_d, stage_sw, cursor, edges, N);

  // h0 = x @ W^T + b
  gemm_kernel<<<(N + 63) / 64, 256, 0, stream>>>(x, W, bias, hA, N);

  // 3 hops, ping-pong hA <-> out
  spmm_kernel<<<(N + 3) / 4, 256, 0, stream>>>(row_ptr, edges, hA, out, N);
  spmm_kernel<<<(N + 3) / 4, 256, 0, stream>>>(row_ptr, edges, out, hA, N);
  spmm_kernel<<<(N + 3) / 4, 256, 0, stream>>>(row_ptr, edges, hA, out, N);
}

// Round 7
// 382.372 us; speedup vs baseline: 1.7504x; 1.7504x over previous
//
#include <hip/hip_runtime.h>

#define N_NODES_C 100000
#define N_EDGES_C 1600000
#define IN_F 128
#define OUT_F 64

#define BIN_SHIFT 9
#define BIN_SZ    512                                  // nodes per bin
#define NBIN      ((N_NODES_C + BIN_SZ - 1) / BIN_SZ)  // 196
#define NCHUNK    256
#define CH        (N_EDGES_C / NCHUNK)                 // 6250 exactly

// ---------------- GEMM: h[n][64] = x[n][128] @ W[64][128]^T + b ----------------
__global__ __launch_bounds__(256) void gemm_kernel(
    const float* __restrict__ x, const float* __restrict__ W,
    const float* __restrict__ bias, float* __restrict__ h, int n) {
  __shared__ float Wt[IN_F * OUT_F];   // [k][o], stride 64, 32 KB
  const int t = threadIdx.x;
  {
    const int o = t & 63;
    const int k4base = t >> 6;
    const float4* Wrow = (const float4*)(W + o * IN_F);
#pragma unroll
    for (int i = 0; i < 8; ++i) {
      int k4 = k4base + i * 4;
      float4 v = Wrow[k4];
      int k = k4 * 4;
      Wt[(k + 0) * OUT_F + o] = v.x;
      Wt[(k + 1) * OUT_F + o] = v.y;
      Wt[(k + 2) * OUT_F + o] = v.z;
      Wt[(k + 3) * OUT_F + o] = v.w;
    }
  }
  __syncthreads();

  const int tx = t & 15;
  const int ty = t >> 4;
  const int node0 = blockIdx.x * 64 + ty * 4;

  bool v0 = node0 + 0 < n, v1 = node0 + 1 < n, v2 = node0 + 2 < n, v3 = node0 + 3 < n;
  const float4* xr0 = (const float4*)(x + (size_t)(v0 ? node0 + 0 : 0) * IN_F);
  const float4* xr1 = (const float4*)(x + (size_t)(v1 ? node0 + 1 : 0) * IN_F);
  const float4* xr2 = (const float4*)(x + (size_t)(v2 ? node0 + 2 : 0) * IN_F);
  const float4* xr3 = (const float4*)(x + (size_t)(v3 ? node0 + 3 : 0) * IN_F);

  float4 acc0 = make_float4(0.f, 0.f, 0.f, 0.f);
  float4 acc1 = acc0, acc2 = acc0, acc3 = acc0;
  const float4* Wt4 = (const float4*)Wt;

#pragma unroll 2
  for (int kc = 0; kc < 32; ++kc) {
    float4 xv0 = xr0[kc];
    float4 xv1 = xr1[kc];
    float4 xv2 = xr2[kc];
    float4 xv3 = xr3[kc];
    float4 w0 = Wt4[(kc * 4 + 0) * 16 + tx];
    float4 w1 = Wt4[(kc * 4 + 1) * 16 + tx];
    float4 w2 = Wt4[(kc * 4 + 2) * 16 + tx];
    float4 w3 = Wt4[(kc * 4 + 3) * 16 + tx];
#define FMA4(A, XV)                                            \
    A.x += XV.x * w0.x + XV.y * w1.x + XV.z * w2.x + XV.w * w3.x; \
    A.y += XV.x * w0.y + XV.y * w1.y + XV.z * w2.y + XV.w * w3.y; \
    A.z += XV.x * w0.z + XV.y * w1.z + XV.z * w2.z + XV.w * w3.z; \
    A.w += XV.x * w0.w + XV.y * w1.w + XV.z * w2.w + XV.w * w3.w;
    FMA4(acc0, xv0)
    FMA4(acc1, xv1)
    FMA4(acc2, xv2)
    FMA4(acc3, xv3)
#undef FMA4
  }

  const float4 bv = ((const float4*)bias)[tx];
  acc0.x += bv.x; acc0.y += bv.y; acc0.z += bv.z; acc0.w += bv.w;
  acc1.x += bv.x; acc1.y += bv.y; acc1.z += bv.z; acc1.w += bv.w;
  acc2.x += bv.x; acc2.y += bv.y; acc2.z += bv.z; acc2.w += bv.w;
  acc3.x += bv.x; acc3.y += bv.y; acc3.z += bv.z; acc3.w += bv.w;

  if (v0) ((float4*)(h + (size_t)(node0 + 0) * OUT_F))[tx] = acc0;
  if (v1) ((float4*)(h + (size_t)(node0 + 1) * OUT_F))[tx] = acc1;
  if (v2) ((float4*)(h + (size_t)(node0 + 2) * OUT_F))[tx] = acc2;
  if (v3) ((float4*)(h + (size_t)(node0 + 3) * OUT_F))[tx] = acc3;
}

// ---------------- CSR build: LDS-binned counting sort ----------------
// Phase 1: per-chunk LDS histogram over 196 bins.
__global__ __launch_bounds__(256) void hist_kernel(
    const int* __restrict__ dst, int* __restrict__ hist) {
  __shared__ int h[NBIN];
  const int t = threadIdx.x;
  for (int i = t; i < NBIN; i += 256) h[i] = 0;
  __syncthreads();
  const int e0 = blockIdx.x * CH;
  for (int i = t; i < CH; i += 256)
    atomicAdd(&h[dst[e0 + i] >> BIN_SHIFT], 1);
  __syncthreads();
  for (int i = t; i < NBIN; i += 256)
    hist[i * NCHUNK + blockIdx.x] = h[i];      // bin-major layout
}

#define RB 256
__global__ __launch_bounds__(RB) void reduce_kernel(
    const int* __restrict__ v, int* __restrict__ blockSums, int n) {
  __shared__ int s[RB];
  int i = blockIdx.x * RB + threadIdx.x;
  s[threadIdx.x] = (i < n) ? v[i] : 0;
  __syncthreads();
  for (int off = RB / 2; off > 0; off >>= 1) {
    if (threadIdx.x < off) s[threadIdx.x] += s[threadIdx.x + off];
    __syncthreads();
  }
  if (threadIdx.x == 0) blockSums[blockIdx.x] = s[0];
}

__global__ __launch_bounds__(512) void scan_partials_kernel(
    const int* __restrict__ blockSums, int* __restrict__ blockOffs, int nb,
    int* __restrict__ total_out) {
  __shared__ int s[512];
  int t = threadIdx.x;
  int v = (t < nb) ? blockSums[t] : 0;
  s[t] = v;
  __syncthreads();
  for (int off = 1; off < 512; off <<= 1) {
    int u = (t >= off) ? s[t - off] : 0;
    __syncthreads();
    s[t] += u;
    __syncthreads();
  }
  if (t < nb) blockOffs[t] = s[t] - v;      // exclusive
  if (t == 511) *total_out = s[511];        // == E (scratch)
}

// Final: exclusive scan of hist -> soff (same layout); binStart[b] = soff[b*NCHUNK].
// One block per bin-row (256 threads == NCHUNK).
__global__ __launch_bounds__(RB) void scan_final_kernel(
    const int* __restrict__ hist, const int* __restrict__ blockOffs,
    int* __restrict__ soff, int* __restrict__ binStart, int n) {
  __shared__ int s[RB];
  int i = blockIdx.x * RB + threadIdx.x;
  int v = (i < n) ? hist[i] : 0;
  s[threadIdx.x] = v;
  __syncthreads();
  for (int off = 1; off < RB; off <<= 1) {
    int u = (threadIdx.x >= off) ? s[threadIdx.x - off] : 0;
    __syncthreads();
    s[threadIdx.x] += u;
    __syncthreads();
  }
  if (i < n) {
    int ex = blockOffs[blockIdx.x] + s[threadIdx.x] - v;
    soff[i] = ex;
    if (threadIdx.x == 0) binStart[blockIdx.x] = ex;   // chunk 0 of this bin
  }
}

// Phase 2: re-read chunk, append records at LDS-cursor positions.
// Each (block,bin) run is a contiguous burst written by ONE CU -> dense writebacks.
__global__ __launch_bounds__(256) void binscatter_kernel(
    const int* __restrict__ src, const int* __restrict__ dst,
    const float* __restrict__ w, const int* __restrict__ soff,
    int* __restrict__ stage_d, int2* __restrict__ stage_sw) {
  __shared__ int lcur[NBIN];
  const int t = threadIdx.x;
  const int c = blockIdx.x;
  for (int i = t; i < NBIN; i += 256) lcur[i] = soff[i * NCHUNK + c];
  __syncthreads();
  const int e0 = c * CH;
  for (int i = t; i < CH; i += 256) {
    int e = e0 + i;
    int d = dst[e];
    int p = atomicAdd(&lcur[d >> BIN_SHIFT], 1);
    stage_d[p]  = d;
    stage_sw[p] = make_int2(src[e] * OUT_F, __float_as_int(w[e]));
  }
}

// Phase 3: one block per bin. LDS count -> LDS scan (row_ptr for free) ->
// place records at exact CSR slots. All traffic within the bin's ~65KB span.
__global__ __launch_bounds__(BIN_SZ) void place_kernel(
    const int* __restrict__ binStart, const int* __restrict__ stage_d,
    const int2* __restrict__ stage_sw, int* __restrict__ row_ptr,
    int2* __restrict__ edges, int n) {
  __shared__ int lcount[BIN_SZ];
  __shared__ int s[BIN_SZ];
  __shared__ int lcur[BIN_SZ];
  const int t = threadIdx.x;
  const int b = blockIdx.x;
  const int base = binStart[b];
  const int end  = (b == NBIN - 1) ? N_EDGES_C : binStart[b + 1];
  const int node0 = b << BIN_SHIFT;

  lcount[t] = 0;
  __syncthreads();
  for (int i = base + t; i < end; i += BIN_SZ)
    atomicAdd(&lcount[stage_d[i] - node0], 1);
  __syncthreads();

  int v = lcount[t];
  s[t] = v;
  __syncthreads();
  for (int off = 1; off < BIN_SZ; off <<= 1) {
    int u = (t >= off) ? s[t - off] : 0;
    __syncthreads();
    s[t] += u;
    __syncthreads();
  }
  int ex = base + s[t] - v;       // exclusive CSR offset for node node0+t
  int node = node0 + t;
  if (node < n) row_ptr[node] = ex;
  lcur[t] = ex;
  __syncthreads();

  for (int i = base + t; i < end; i += BIN_SZ) {
    int d = stage_d[i];
    int p = atomicAdd(&lcur[d - node0], 1);
    edges[p] = stage_sw[i];
  }
  if (b == NBIN - 1 && t == 0) row_ptr[n] = N_EDGES_C;
}

// ---------------- SpMM hop ----------------
__global__ __launch_bounds__(256) void spmm_kernel(
    const int* __restrict__ row_ptr, const int2* __restrict__ edges,
    const float* __restrict__ hin, float* __restrict__ hout, int n) {
  const int node = blockIdx.x * 4 + (threadIdx.x >> 6);
  const int lane = threadIdx.x & 63;
  const int grp  = lane >> 4;        // 0..3 edge group
  const int fl   = lane & 15;        // feature quad
  if (node >= n) return;
  const int beg = row_ptr[node];
  const int end = row_ptr[node + 1];

  float4 acc = make_float4(0.f, 0.f, 0.f, 0.f);
  int j = beg + grp;
  for (; j + 4 < end; j += 8) {
    int2 e0 = edges[j];
    int2 e1 = edges[j + 4];
    float4 h0 = ((const float4*)(hin + e0.x))[fl];
    float4 h1 = ((const float4*)(hin + e1.x))[fl];
    float w0 = __int_as_float(e0.y);
    float w1 = __int_as_float(e1.y);
    acc.x += w0 * h0.x + w1 * h1.x;
    acc.y += w0 * h0.y + w1 * h1.y;
    acc.z += w0 * h0.z + w1 * h1.z;
    acc.w += w0 * h0.w + w1 * h1.w;
  }
  if (j < end) {
    int2 e0 = edges[j];
    float4 h0 = ((const float4*)(hin + e0.x))[fl];
    float w0 = __int_as_float(e0.y);
    acc.x += w0 * h0.x;
    acc.y += w0 * h0.y;
    acc.z += w0 * h0.z;
    acc.w += w0 * h0.w;
  }

  acc.x += __shfl_down(acc.x, 32);
  acc.y += __shfl_down(acc.y, 32);
  acc.z += __shfl_down(acc.z, 32);
  acc.w += __shfl_down(acc.w, 32);
  acc.x += __shfl_down(acc.x, 16);
  acc.y += __shfl_down(acc.y, 16);
  acc.z += __shfl_down(acc.z, 16);
  acc.w += __shfl_down(acc.w, 16);

  if (grp == 0) {
    ((float4*)(hout + (size_t)node * OUT_F))[fl] = acc;
  }
}

extern "C" void kernel_launch(void* const* d_in, const int* in_sizes, int n_in,
                              void* d_out, int out_size, void* d_ws, size_t ws_size,
                              hipStream_t stream) {
  const float* x    = (const float*)d_in[0];
  const int*   ei   = (const int*)d_in[1];   // int32 (harness materializes ints as int32)
  const float* ew   = (const float*)d_in[2];
  const float* W    = (const float*)d_in[3];
  const float* bias = (const float*)d_in[4];
  float* out = (float*)d_out;

  const int N = N_NODES_C;
  const int E = N_EDGES_C;
  const int* src = ei;
  const int* dst = ei + E;
  const int NH = NBIN * NCHUNK;        // 50176 hist entries
  const int NRB = NH / RB;             // 196 reduce blocks

  char* p = (char*)d_ws;
  auto carve = [&](size_t bytes) {
    void* r = (void*)p;
    p += (bytes + 255) & ~(size_t)255;
    return r;
  };
  float* hA        = (float*)carve((size_t)N * OUT_F * 4);
  int*   row_ptr   = (int*)  carve((size_t)(N + 1) * 4);
  int2*  edges     = (int2*) carve((size_t)E * 8);
  int*   hist      = (int*)  carve((size_t)NH * 4);
  int*   soff      = (int*)  carve((size_t)NH * 4);
  int*   blockSums = (int*)  carve((size_t)NRB * 4);
  int*   blockOffs = (int*)  carve((size_t)NRB * 4);
  int*   binStart  = (int*)  carve((size_t)(NBIN + 1) * 4);  // +1 scratch for total

  // staging in d_out (free scratch until spmm hop 1): sw 12.8MB + d 6.4MB
  int2* stage_sw = (int2*)d_out;
  int*  stage_d  = (int*)((char*)d_out + (size_t)E * 8);

  // CSR build (no global atomics)
  hist_kernel         <<<NCHUNK, 256, 0, stream>>>(dst, hist);
  reduce_kernel       <<<NRB, RB, 0, stream>>>(hist, blockSums, NH);
  scan_partials_kernel<<<1, 512, 0, stream>>>(blockSums, blockOffs, NRB, &binStart[NBIN]);
  scan_final_kernel   <<<NRB, RB, 0, stream>>>(hist, blockOffs, soff, binStart, NH);
  binscatter_kernel   <<<NCHUNK, 256, 0, stream>>>(src, dst, ew, soff, stage_d, stage_sw);
  place_kernel        <<<NBIN, BIN_SZ, 0, stream>>>(binStart, stage_d, stage_sw,
                                                    row_ptr, edges, N);

  // h0 = x @ W^T + b
  gemm_kernel<<<(N + 63) / 64, 256, 0, stream>>>(x, W, bias, hA, N);

  // 3 hops, ping-pong hA <-> out
  spmm_kernel<<<(N + 3) / 4, 256, 0, stream>>>(row_ptr, edges, hA, out, N);
  spmm_kernel<<<(N + 3) / 4, 256, 0, stream>>>(row_ptr, edges, out, hA, N);
  spmm_kernel<<<(N + 3) / 4, 256, 0, stream>>>(row_ptr, edges, hA, out, N);
}